// Round 4
// baseline (305.347 us; speedup 1.0000x reference)
//
#include <hip/hip_runtime.h>
#include <hip/hip_fp16.h>

#define DIM   256
#define HW_   1024
#define NROWS 32768
#define KEMB  4096

// ---------------- ws layout ----------------
// [0,       131072)  int    idx[32768]
// [131072,  262144)  float  S[32768]
// [262144,  278528)  float  E[4096]
// [278528,  278536)  double loss_sum
// [278536,  278540)  int    done
// [278592,  409664)  int    cnt[32768]
// [540736,  1589312) int    cand[32768][8]
// [1589312, 3686464) short  ebuf[1048576]  (bf16, 16x16-frag-major, 2 MB)
#define WS_S_OFF    131072
#define WS_E_OFF    262144
#define WS_LOSS_OFF 278528
#define WS_DONE_OFF 278536
#define WS_CNT_OFF  278592
#define WS_CAND_OFF 540736
#define WS_EBUF_OFF 1589312
#define WS_NEEDED   3686464
#define RESCUE_W    1.5e-4f

typedef __attribute__((ext_vector_type(8))) short bf16x8;
typedef __attribute__((ext_vector_type(4))) float f32x4;
typedef __attribute__((ext_vector_type(4))) unsigned short u16x4;

__device__ __forceinline__ unsigned short f2bf(float v) {
  unsigned u = __float_as_uint(v);
  return (unsigned short)((u + 0x7FFFu + ((u >> 16) & 1u)) >> 16);
}

// min over the 16-lane DPP row (lanes quad*16 + 0..15) via ROW_ROR rotations.
// Pure VALU (no ds_swizzle / LDS pipe). All 16 lanes end with the row min.
__device__ __forceinline__ float rowmin16_dpp(float v) {
  int x = __float_as_int(v), y;
  y = __builtin_amdgcn_update_dpp(0, x, 0x121, 0xF, 0xF, true);  // ROW_ROR:1
  x = __float_as_int(fminf(__int_as_float(x), __int_as_float(y)));
  y = __builtin_amdgcn_update_dpp(0, x, 0x122, 0xF, 0xF, true);  // ROW_ROR:2
  x = __float_as_int(fminf(__int_as_float(x), __int_as_float(y)));
  y = __builtin_amdgcn_update_dpp(0, x, 0x124, 0xF, 0xF, true);  // ROW_ROR:4
  x = __float_as_int(fminf(__int_as_float(x), __int_as_float(y)));
  y = __builtin_amdgcn_update_dpp(0, x, 0x128, 0xF, 0xF, true);  // ROW_ROR:8
  x = __float_as_int(fminf(__int_as_float(x), __int_as_float(y)));
  return __int_as_float(x);
}

// ---------- numpy-pairwise row sums of squares ----------
__device__ __forceinline__ float np_sumsq_128(const float* q, int stride) {
#pragma clang fp contract(off)
  float r[8];
#pragma unroll
  for (int i = 0; i < 8; ++i) { float v = q[i * stride]; r[i] = v * v; }
  for (int blk = 8; blk < 128; blk += 8) {
#pragma unroll
    for (int i = 0; i < 8; ++i) {
      float v = q[(blk + i) * stride];
      float sq = v * v;
      r[i] = r[i] + sq;
    }
  }
  return ((r[0] + r[1]) + (r[2] + r[3])) + ((r[4] + r[5]) + (r[6] + r[7]));
}

// ---------- prep: norms+init [0,144) + 16x16-frag pack [144,656) ----------
// pack (R5-proven): tile (g16, ks): lane l holds e[j = g16*16 + (l&15)]
// [k = ks*32 + (l>>4)*8 + i]; flat short offset = u*8, u = (g16*8+ks)*64+l.
__global__ __launch_bounds__(256) void prep_kernel(
    const float* __restrict__ z, const float* __restrict__ emb,
    float* __restrict__ S, float* __restrict__ E, short* __restrict__ ebuf,
    double* __restrict__ loss_sum, int* __restrict__ done, int do_filter) {
#pragma clang fp contract(off)
  if (blockIdx.x < 144) {
    int t = blockIdx.x * 256 + threadIdx.x;
    if (t == 0) { loss_sum[0] = 0.0; done[0] = 0; }
    if (t < NROWS) {
      int b = t >> 10, hw = t & 1023;
      const float* p = z + (size_t)b * (DIM * HW_) + hw;
      float s0 = np_sumsq_128(p, HW_);
      float s1 = np_sumsq_128(p + 128 * HW_, HW_);
      S[t] = s0 + s1;
    } else if (t < NROWS + KEMB) {
      int j = t - NROWS;
      const float* p = emb + (size_t)j * DIM;
      float s0 = np_sumsq_128(p, 1);
      float s1 = np_sumsq_128(p + 128, 1);
      E[j] = s0 + s1;
    }
  } else {
    if (!do_filter) return;
    int u = (blockIdx.x - 144) * 256 + threadIdx.x;   // 0..131071
    int lane = u & 63;
    int ks = (u >> 6) & 7;
    int g16 = u >> 9;
    int j = g16 * 16 + (lane & 15);
    int kb = ks * 32 + (lane >> 4) * 8;
    const float* p = emb + (size_t)j * DIM + kb;
    short out[8];
#pragma unroll
    for (int i = 0; i < 8; ++i) out[i] = (short)f2bf(p[i]);
    *(bf16x8*)(ebuf + (size_t)u * 8) = *(bf16x8*)out;
  }
}

// ---------- fused filter v5: sweep-1 tile skipping via per-(row,jt) mins ----
// Structure as v4 (512 blk x 8 waves, 64 rows x 4096 j, jt=4, frag-major LDS
// A). NEW: sweep 0 records, per (row, 16-j tile), a CONSERVATIVE (rounded-
// down) fp16 tile-min: tm = rowmin16_dpp(g) over the 16 j-columns (DPP
// ROW_ROR min - VALU pipe, not LDS), stored as f16_rn((tm - 2e-5)*1024)
// -> stored/1024 <= g - 1e-5 for every g in the tile (f16 rel err 2^-11,
// |g|~0.01 -> err <= 1e-5; x1024 avoids the denormal-flush zone).
// Sweep 1 tests per grp: lane l checks row l's 4 cells vs T =
// (thr[l]-1e-5)*1024; 4 ballots -> wave-uniform jt mask; skip inactive jt
// (g <= thr there is impossible: stored > T => min_tile > thr). Skipped
// tiles contain no emissions -> candidate set and cnt EXACTLY unchanged.
// Expected active fraction ~0.3-0.4 -> sweep-1 MFMA + B-loads cut ~2.6x.
// s_setprio(1) wraps MFMA clusters (waves are barrier-free in the main
// loops -> role diversity, the measured-positive setprio regime).
// Regs: sweep1 live ~112 (acc64+av16+bfr8+thrv16+misc) -> (512,4) pins
// <=128 = 2 blocks/CU. LDS 70.7 KB/block -> 141 KB/CU, 2 blocks fit.
__global__ __launch_bounds__(512, 4) void filter2_kernel(
    const float* __restrict__ z, const short* __restrict__ ebuf,
    const float* __restrict__ E, int* __restrict__ cnt_g,
    int* __restrict__ cand_g) {
  __shared__ __align__(16) short Ab[32 * 512];        // 32 KB, fragment-major
  __shared__ unsigned short skipmin[64][260];         // 33.2 KB, f16 tile-mins
  __shared__ float rowmin_l[64][8];
  __shared__ float thr_l[64];
  __shared__ int   cnt_l[64];
  __shared__ int   cand_l[64][8];

  const int t = threadIdx.x;
  const int w = t >> 6, lane = t & 63;
  const int quad = lane >> 4, l16 = lane & 15;
  const int nb = blockIdx.x * 64;
  const int b = nb >> 10, hwb = nb & 1023;   // 64 | 1024: no b straddle

  // ---- cooperative A stage: wave w converts k-slice ks=w, mt=0..3 ----
  {
    const float* zb2 = z + (size_t)b * (DIM * HW_) + hwb;
    const int k0 = w * 32 + quad * 8;
#pragma unroll
    for (int mt = 0; mt < 4; ++mt) {
      const int r = mt * 16 + l16;
      short tmp[8];
#pragma unroll
      for (int i = 0; i < 8; ++i)
        tmp[i] = (short)f2bf(zb2[(size_t)(k0 + i) * HW_ + r]);
      *(bf16x8*)(Ab + ((mt * 8 + w) * 64 + lane) * 8) = *(bf16x8*)tmp;
    }
  }
  __syncthreads();

  const f32x4 zero = {0.0f, 0.0f, 0.0f, 0.0f};
  const short* Abl = Ab + lane * 8;          // per-thread frag base

  // ================= sweep 0: row minima + tile-min record =================
  float runmin[4][4];
#pragma unroll
  for (int mt = 0; mt < 4; ++mt)
#pragma unroll
    for (int rg = 0; rg < 4; ++rg) runmin[mt][rg] = 3.0e38f;

#pragma unroll 1
  for (int grp = 0; grp < 8; ++grp) {
    const int jb = w * 512 + grp * 64;
    const int g16b = jb >> 4;
    const int cellb = w * 32 + grp * 4;
    f32x4 acc[4][4];
#pragma unroll
    for (int jt = 0; jt < 4; ++jt)
#pragma unroll
      for (int mt = 0; mt < 4; ++mt) acc[jt][mt] = zero;
#pragma unroll 1
    for (int ks = 0; ks < 8; ++ks) {
      bf16x8 av[4];
#pragma unroll
      for (int mt = 0; mt < 4; ++mt)
        av[mt] = *(const bf16x8*)(Abl + (mt * 8 + ks) * 512);
      __builtin_amdgcn_s_setprio(1);
#pragma unroll
      for (int jt = 0; jt < 4; ++jt) {
        bf16x8 bfr = *(const bf16x8*)(ebuf +
            ((size_t)(g16b + jt) * 8 + ks) * 512 + lane * 8);
#pragma unroll
        for (int mt = 0; mt < 4; ++mt)
          acc[jt][mt] = __builtin_amdgcn_mfma_f32_16x16x32_bf16(
              av[mt], bfr, acc[jt][mt], 0, 0, 0);
      }
      __builtin_amdgcn_s_setprio(0);
    }
    float Ejv[4];
#pragma unroll
    for (int jt = 0; jt < 4; ++jt) Ejv[jt] = E[jb + jt * 16 + l16];
#pragma unroll
    for (int mt = 0; mt < 4; ++mt)
#pragma unroll
      for (int rg = 0; rg < 4; ++rg) {
        u16x4 hv;
#pragma unroll
        for (int jt = 0; jt < 4; ++jt) {
          float g = fmaf(-2.0f, acc[jt][mt][rg], Ejv[jt]);
          runmin[mt][rg] = fminf(runmin[mt][rg], g);
          float tm = rowmin16_dpp(g);
          hv[jt] = __half_as_ushort(
              __float2half_rn((tm - 2.0e-5f) * 1024.0f));
        }
        if (l16 == 0)
          *(u16x4*)&skipmin[mt * 16 + quad * 4 + rg][cellb] = hv;
      }
  }
  // reduce over the 16 j-columns
#pragma unroll
  for (int mt = 0; mt < 4; ++mt)
#pragma unroll
    for (int rg = 0; rg < 4; ++rg) {
      float m = runmin[mt][rg];
#pragma unroll
      for (int mask = 1; mask <= 8; mask <<= 1)
        m = fminf(m, __shfl_xor(m, mask, 64));
      runmin[mt][rg] = m;
    }
  if (l16 == 0) {
#pragma unroll
    for (int mt = 0; mt < 4; ++mt)
#pragma unroll
      for (int rg = 0; rg < 4; ++rg)
        rowmin_l[mt * 16 + quad * 4 + rg][w] = runmin[mt][rg];
  }
  __syncthreads();
  if (t < 64) {
    float m0 = fminf(fminf(rowmin_l[t][0], rowmin_l[t][1]),
                     fminf(rowmin_l[t][2], rowmin_l[t][3]));
    float m1 = fminf(fminf(rowmin_l[t][4], rowmin_l[t][5]),
                     fminf(rowmin_l[t][6], rowmin_l[t][7]));
    thr_l[t] = fminf(m0, m1) + RESCUE_W;
    cnt_l[t] = 0;
  }
  __syncthreads();
  float thrv[4][4];
#pragma unroll
  for (int mt = 0; mt < 4; ++mt)
#pragma unroll
    for (int rg = 0; rg < 4; ++rg)
      thrv[mt][rg] = thr_l[mt * 16 + quad * 4 + rg];

  // ================= sweep 1: emission over active tiles only =============
#pragma unroll 1
  for (int grp = 0; grp < 8; ++grp) {
    const int jb = w * 512 + grp * 64;
    const int g16b = jb >> 4;
    const int cellb = w * 32 + grp * 4;

    // per-grp activity mask: lane l tests row l's 4 jt cells (conservative)
    int am = 0;
    {
      u16x4 sv = *(const u16x4*)&skipmin[lane][cellb];
      float T = (thr_l[lane] - 1.0e-5f) * 1024.0f;
      if (__any(__half2float(__ushort_as_half(sv[0])) <= T)) am |= 1;
      if (__any(__half2float(__ushort_as_half(sv[1])) <= T)) am |= 2;
      if (__any(__half2float(__ushort_as_half(sv[2])) <= T)) am |= 4;
      if (__any(__half2float(__ushort_as_half(sv[3])) <= T)) am |= 8;
    }
    if (am == 0) continue;

    f32x4 acc[4][4];
#pragma unroll
    for (int jt = 0; jt < 4; ++jt)
#pragma unroll
      for (int mt = 0; mt < 4; ++mt) acc[jt][mt] = zero;
#pragma unroll 1
    for (int ks = 0; ks < 8; ++ks) {
      bf16x8 av[4];
#pragma unroll
      for (int mt = 0; mt < 4; ++mt)
        av[mt] = *(const bf16x8*)(Abl + (mt * 8 + ks) * 512);
      __builtin_amdgcn_s_setprio(1);
#pragma unroll
      for (int jt = 0; jt < 4; ++jt) {
        if (am & (1 << jt)) {
          bf16x8 bfr = *(const bf16x8*)(ebuf +
              ((size_t)(g16b + jt) * 8 + ks) * 512 + lane * 8);
#pragma unroll
          for (int mt = 0; mt < 4; ++mt)
            acc[jt][mt] = __builtin_amdgcn_mfma_f32_16x16x32_bf16(
                av[mt], bfr, acc[jt][mt], 0, 0, 0);
        }
      }
      __builtin_amdgcn_s_setprio(0);
    }
#pragma unroll
    for (int jt = 0; jt < 4; ++jt) {
      if (!(am & (1 << jt))) continue;
      int jcol = jb + jt * 16 + l16;
      float Ej = E[jcol];
#pragma unroll
      for (int mt = 0; mt < 4; ++mt)
#pragma unroll
        for (int rg = 0; rg < 4; ++rg) {
          float g = fmaf(-2.0f, acc[jt][mt][rg], Ej);
          if (g <= thrv[mt][rg]) {
            int rl = mt * 16 + quad * 4 + rg;
            int slot = atomicAdd(&cnt_l[rl], 1);
            if (slot < 8) cand_l[rl][slot] = jcol;
          }
        }
    }
  }
  __syncthreads();
  if (t < 64) {
    int c = cnt_l[t];
    cnt_g[nb + t] = c;
    int cc = c > 8 ? 8 : c;
    for (int p = 0; p < cc; ++p) cand_g[(size_t)(nb + t) * 8 + p] = cand_l[t][p];
  }
}

// ---------- rescue: exact np-order chains over per-row candidates ----------
__global__ __launch_bounds__(256) void exact_cand_kernel(
    const float* __restrict__ z, const float* __restrict__ emb,
    const float* __restrict__ S, const float* __restrict__ E,
    const int* __restrict__ cnt_g, const int* __restrict__ cand_g,
    int* __restrict__ idx_out, float* __restrict__ idxf_out) {
  int row = blockIdx.x * 256 + threadIdx.x;
  int b = row >> 10, hw = row & 1023;
  const float* zr = z + (size_t)b * (DIM * HW_) + hw;   // z[k] at zr[k*1024]
  const float s = S[row];
  int c = cnt_g[row];
  float bd = 3.0e38f; int bj = 0x7fffffff;
  if (c <= 8) {
    for (int p = 0; p < c; ++p) {
      int j = cand_g[(size_t)row * 8 + p];
      const float* e = emb + (size_t)j * DIM;
      float acc = 0.0f;
#pragma unroll 8
      for (int k4 = 0; k4 < 64; ++k4) {          // sequential k ascending
        float4 ev = *(const float4*)(e + k4 * 4);
        acc = fmaf(zr[(size_t)(k4 * 4 + 0) * HW_], ev.x, acc);
        acc = fmaf(zr[(size_t)(k4 * 4 + 1) * HW_], ev.y, acc);
        acc = fmaf(zr[(size_t)(k4 * 4 + 2) * HW_], ev.z, acc);
        acc = fmaf(zr[(size_t)(k4 * 4 + 3) * HW_], ev.w, acc);
      }
      float d = fmaf(-2.0f, acc, s + E[j]);
      if (d < bd || (d == bd && j < bj)) { bd = d; bj = j; }
    }
  } else {
    for (int j = 0; j < KEMB; ++j) {             // overflow fallback (P~0)
      const float* e = emb + (size_t)j * DIM;
      float acc = 0.0f;
      for (int k4 = 0; k4 < 64; ++k4) {
        float4 ev = *(const float4*)(e + k4 * 4);
        acc = fmaf(zr[(size_t)(k4 * 4 + 0) * HW_], ev.x, acc);
        acc = fmaf(zr[(size_t)(k4 * 4 + 1) * HW_], ev.y, acc);
        acc = fmaf(zr[(size_t)(k4 * 4 + 2) * HW_], ev.z, acc);
        acc = fmaf(zr[(size_t)(k4 * 4 + 3) * HW_], ev.w, acc);
      }
      float d = fmaf(-2.0f, acc, s + E[j]);
      if (d < bd || (d == bd && j < bj)) { bd = d; bj = j; }
    }
  }
  idx_out[row] = bj;
  idxf_out[row] = (float)bj;
}

// ---------- fallback fp32 kernel (R2 version, known-passing) ----------
#define RT 64
#define JT 256
#define KC 16
__global__ __launch_bounds__(256, 2) void dist_argmin_kernel(
    const float* __restrict__ z, const float* __restrict__ emb,
    const float* __restrict__ S, const float* __restrict__ E,
    int* __restrict__ idx_out, float* __restrict__ idxf_out) {
  __shared__ float zt[DIM * RT];
  __shared__ float et[KC * JT];
  const int t  = threadIdx.x;
  const int g  = t & 31;
  const int tr = t >> 5;
  const int nb = blockIdx.x * RT;
  const int b  = nb >> 10;
  const int hwb = nb & 1023;
  const float* zb = z + (size_t)b * (DIM * HW_) + hwb;
#pragma unroll
  for (int i = 0; i < 16; ++i) {
    int flat = t + i * 256;
    int k  = flat >> 4;
    int r4 = flat & 15;
    float4 v = *(const float4*)(zb + (size_t)k * HW_ + r4 * 4);
    *(float4*)(zt + flat * 4) = v;
  }
  float bestd[8];
  int   bestj[8];
#pragma unroll
  for (int i = 0; i < 8; ++i) { bestd[i] = 3.0e38f; bestj[i] = 0; }
  float Sreg[8];
#pragma unroll
  for (int rr = 0; rr < 8; ++rr) Sreg[rr] = S[nb + tr * 8 + rr];
  float4 pf[4];
#pragma unroll
  for (int q = 0; q < 4; ++q) {
    int cid = q * 256 + t;
    pf[q] = *(const float4*)(emb + (size_t)(cid >> 2) * DIM + (cid & 3) * 4);
  }
  for (int jt = 0; jt < KEMB / JT; ++jt) {
    float acc[8][8];
#pragma unroll
    for (int rr = 0; rr < 8; ++rr)
#pragma unroll
      for (int c = 0; c < 8; ++c) acc[rr][c] = 0.0f;
    for (int kc = 0; kc < DIM / KC; ++kc) {
      __syncthreads();
#pragma unroll
      for (int q = 0; q < 4; ++q) {
        int cid = q * 256 + t;
        int j = cid >> 2, k4 = cid & 3;
        et[(k4 * 4 + 0) * JT + j] = pf[q].x;
        et[(k4 * 4 + 1) * JT + j] = pf[q].y;
        et[(k4 * 4 + 2) * JT + j] = pf[q].z;
        et[(k4 * 4 + 3) * JT + j] = pf[q].w;
      }
      int s = jt * (DIM / KC) + kc + 1;
      if (s < (KEMB / JT) * (DIM / KC)) {
        int njt = s >> 4, nkc = s & 15;
        const float* base = emb + (size_t)njt * JT * DIM + nkc * KC;
#pragma unroll
        for (int q = 0; q < 4; ++q) {
          int cid = q * 256 + t;
          pf[q] = *(const float4*)(base + (size_t)(cid >> 2) * DIM + (cid & 3) * 4);
        }
      }
      __syncthreads();
      const float* ztk = zt + (kc * KC) * RT;
#pragma unroll
      for (int kk = 0; kk < KC; ++kk) {
        float4 z0 = *(const float4*)(ztk + kk * RT + tr * 8);
        float4 z1 = *(const float4*)(ztk + kk * RT + tr * 8 + 4);
        float2 e0 = *(const float2*)(et + kk * JT + g * 2);
        float2 e1 = *(const float2*)(et + kk * JT + 64 + g * 2);
        float2 e2 = *(const float2*)(et + kk * JT + 128 + g * 2);
        float2 e3 = *(const float2*)(et + kk * JT + 192 + g * 2);
        float zr[8] = {z0.x, z0.y, z0.z, z0.w, z1.x, z1.y, z1.z, z1.w};
        float ev[8] = {e0.x, e0.y, e1.x, e1.y, e2.x, e2.y, e3.x, e3.y};
#pragma unroll
        for (int rr = 0; rr < 8; ++rr)
#pragma unroll
          for (int c = 0; c < 8; ++c)
            acc[rr][c] = fmaf(zr[rr], ev[c], acc[rr][c]);
      }
    }
    int jb = jt * JT;
    float Ereg[8];
#pragma unroll
    for (int c = 0; c < 8; ++c)
      Ereg[c] = E[jb + (c >> 1) * 64 + g * 2 + (c & 1)];
#pragma unroll
    for (int rr = 0; rr < 8; ++rr)
#pragma unroll
      for (int c = 0; c < 8; ++c) {
        float A = Sreg[rr] + Ereg[c];
        float d = fmaf(-2.0f, acc[rr][c], A);
        int j = jb + (c >> 1) * 64 + g * 2 + (c & 1);
        if (d < bestd[rr] || (d == bestd[rr] && j < bestj[rr])) {
          bestd[rr] = d; bestj[rr] = j;
        }
      }
  }
  __syncthreads();
  float* rd = et;
  int*   rj = (int*)(et + 2048);
#pragma unroll
  for (int rr = 0; rr < 8; ++rr) {
    rd[(tr * 8 + rr) * 32 + g] = bestd[rr];
    rj[(tr * 8 + rr) * 32 + g] = bestj[rr];
  }
  __syncthreads();
  if (t < RT) {
    float bd = rd[t * 32];
    int   bj = rj[t * 32];
    for (int c = 1; c < 32; ++c) {
      float d2 = rd[t * 32 + c];
      int   j2 = rj[t * 32 + c];
      if (d2 < bd || (d2 == bd && j2 < bj)) { bd = d2; bj = j2; }
    }
    idx_out[nb + t]  = bj;
    idxf_out[nb + t] = (float)bj;
  }
}

// ---------- epilogue v2 (R9-proven): LDS-staged gather + STE + loss ----------
#define EPAD 257
__global__ __launch_bounds__(256) void epilogue_kernel(
    const float* __restrict__ z, const float* __restrict__ emb,
    const int* __restrict__ idx, float* __restrict__ out0,
    double* __restrict__ loss_sum, int* __restrict__ done,
    float* __restrict__ out_loss) {
#pragma clang fp contract(off)
  __shared__ float eq[64 * EPAD];
  __shared__ int   iv_l[64];
  __shared__ double wsum[4];
  const int t = threadIdx.x, w = t >> 6, lane = t & 63;
  const int nb = blockIdx.x * 64;
  const int b = nb >> 10, hwb = nb & 1023;

  if (t < 64) iv_l[t] = idx[nb + t];
  __syncthreads();
  const float4* emb4 = (const float4*)emb;
#pragma unroll
  for (int i = 0; i < 16; ++i) {
    int r = w * 16 + i;
    float4 v = emb4[(size_t)iv_l[r] * 64 + lane];
    *(float4*)(eq + r * EPAD + lane * 4) = v;
  }
  __syncthreads();

  double acc = 0.0;
  const float* zb = z + (size_t)b * (DIM * HW_) + hwb;
  float* ob = out0 + (size_t)b * (DIM * HW_) + hwb;
  for (int dc = 0; dc < 64; ++dc) {
    int d = dc * 4 + w;
    float zp = zb[(size_t)d * HW_ + lane];
    float zq = eq[lane * EPAD + d];
    float td = zq - zp;                   // fl(z_q - zp)
    ob[(size_t)d * HW_ + lane] = zp + td; // fl(zp + fl(z_q - zp))
    acc += (double)(td * td);
  }
#pragma unroll
  for (int off = 32; off > 0; off >>= 1) acc += __shfl_down(acc, off, 64);
  if (lane == 0) wsum[w] = acc;
  __syncthreads();
  if (t == 0) {
    double bsum = (wsum[0] + wsum[1]) + (wsum[2] + wsum[3]);
    atomicAdd(loss_sum, bsum);
    __threadfence();
    int prev = atomicAdd(done, 1);
    if (prev == 511) {
      double m = loss_sum[0] / 8388608.0;
      float mf = (float)m;
      float bb = 10.0f * mf;
      out_loss[0] = mf + bb;
    }
  }
}

extern "C" void kernel_launch(void* const* d_in, const int* in_sizes, int n_in,
                              void* d_out, int out_size, void* d_ws, size_t ws_size,
                              hipStream_t stream) {
  const float* z   = (const float*)d_in[0];
  const float* emb = (const float*)d_in[1];
  float* out = (float*)d_out;
  char* ws = (char*)d_ws;
  int*      idx  = (int*)ws;
  float*    S    = (float*)(ws + WS_S_OFF);
  float*    E    = (float*)(ws + WS_E_OFF);
  double*   ls   = (double*)(ws + WS_LOSS_OFF);
  int*      done = (int*)(ws + WS_DONE_OFF);
  int*      cnt  = (int*)(ws + WS_CNT_OFF);
  int*      cand = (int*)(ws + WS_CAND_OFF);
  short*    ebuf = (short*)(ws + WS_EBUF_OFF);

  const int do_filter = (ws_size >= (size_t)WS_NEEDED) ? 1 : 0;

  prep_kernel<<<656, 256, 0, stream>>>(z, emb, S, E, ebuf, ls, done, do_filter);

  if (do_filter) {
    filter2_kernel<<<512, 512, 0, stream>>>(z, ebuf, E, cnt, cand);
    exact_cand_kernel<<<128, 256, 0, stream>>>(z, emb, S, E, cnt, cand, idx,
                                               out + 8388609);
  } else {
    dist_argmin_kernel<<<NROWS / RT, 256, 0, stream>>>(z, emb, S, E, idx,
                                                       out + 8388609);
  }

  epilogue_kernel<<<512, 256, 0, stream>>>(z, emb, idx, out, ls, done,
                                           out + 8388608);
}

// Round 5
// 263.304 us; speedup vs baseline: 1.1597x; 1.1597x over previous
//
#include <hip/hip_runtime.h>

#define DIM   256
#define HW_   1024
#define NROWS 32768
#define KEMB  4096

// ---------------- ws layout ----------------
// [0,       131072)  int    idx[32768]
// [131072,  262144)  float  S[32768]   (fallback path only)
// [262144,  278528)  float  E[4096]
// [278528,  278536)  double loss_sum
// [278536,  278540)  int    done
// [278592,  409664)  int    cnt[32768]
// [540736,  1589312) int    cand[32768][8]
// [1589312, 3686464) short  ebuf[1048576]  (bf16, 16x16-frag-major, 2 MB)
#define WS_S_OFF    131072
#define WS_E_OFF    262144
#define WS_LOSS_OFF 278528
#define WS_DONE_OFF 278536
#define WS_CNT_OFF  278592
#define WS_CAND_OFF 540736
#define WS_EBUF_OFF 1589312
#define WS_NEEDED   3686464
#define RESCUE_W    1.5e-4f

typedef __attribute__((ext_vector_type(8))) short bf16x8;
typedef __attribute__((ext_vector_type(4))) float f32x4;

__device__ __forceinline__ unsigned short f2bf(float v) {
  unsigned u = __float_as_uint(v);
  return (unsigned short)((u + 0x7FFFu + ((u >> 16) & 1u)) >> 16);
}

// ---------- numpy-pairwise row sums of squares ----------
__device__ __forceinline__ float np_sumsq_128(const float* q, int stride) {
#pragma clang fp contract(off)
  float r[8];
#pragma unroll
  for (int i = 0; i < 8; ++i) { float v = q[i * stride]; r[i] = v * v; }
  for (int blk = 8; blk < 128; blk += 8) {
#pragma unroll
    for (int i = 0; i < 8; ++i) {
      float v = q[(blk + i) * stride];
      float sq = v * v;
      r[i] = r[i] + sq;
    }
  }
  return ((r[0] + r[1]) + (r[2] + r[3])) + ((r[4] + r[5]) + (r[6] + r[7]));
}

// ---------- prep v2: init + E norms (+S only on fallback path) + pack ------
// Filter path no longer needs S (exact_cand recomputes it bit-identically
// from its LDS-staged z tile) -> skip the 134 MB z read entirely.
// pack (R5-proven): tile (g16, ks): lane l holds e[j = g16*16 + (l&15)]
// [k = ks*32 + (l>>4)*8 + i]; flat short offset = u*8, u = (g16*8+ks)*64+l.
__global__ __launch_bounds__(256) void prep_kernel(
    const float* __restrict__ z, const float* __restrict__ emb,
    float* __restrict__ S, float* __restrict__ E, short* __restrict__ ebuf,
    double* __restrict__ loss_sum, int* __restrict__ done, int do_filter) {
#pragma clang fp contract(off)
  if (blockIdx.x < 144) {
    int t = blockIdx.x * 256 + threadIdx.x;
    if (t == 0) { loss_sum[0] = 0.0; done[0] = 0; }
    if (t < NROWS) {
      if (!do_filter) {
        int b = t >> 10, hw = t & 1023;
        const float* p = z + (size_t)b * (DIM * HW_) + hw;
        float s0 = np_sumsq_128(p, HW_);
        float s1 = np_sumsq_128(p + 128 * HW_, HW_);
        S[t] = s0 + s1;
      }
    } else if (t < NROWS + KEMB) {
      int j = t - NROWS;
      const float* p = emb + (size_t)j * DIM;
      float s0 = np_sumsq_128(p, 1);
      float s1 = np_sumsq_128(p + 128, 1);
      E[j] = s0 + s1;
    }
  } else {
    if (!do_filter) return;
    int u = (blockIdx.x - 144) * 256 + threadIdx.x;   // 0..131071
    int lane = u & 63;
    int ks = (u >> 6) & 7;
    int g16 = u >> 9;
    int j = g16 * 16 + (lane & 15);
    int kb = ks * 32 + (lane >> 4) * 8;
    const float* p = emb + (size_t)j * DIM + kb;
    short out[8];
#pragma unroll
    for (int i = 0; i < 8; ++i) out[i] = (short)f2bf(p[i]);
    *(bf16x8*)(ebuf + (size_t)u * 8) = *(bf16x8*)out;
  }
}

// ---------- fused filter (R3-proven, 133 us): jt=4, frag-major LDS A -------
// 512 blocks x 8 waves; block = 64 rows, full 4096 j; wave w owns j-slice
// [w*512,+512) = 8 groups of 64 j. A staged ONCE per block as bf16 MFMA
// fragments in LDS (fragment-major, = ebuf layout): frag f=(mt*8+ks) at
// Ab + f*512 + lane*8 shorts -> ds_read_b128, per-thread base + imm offset.
// jt=4: 4 av + 4 bfr LDS reads / 16 MFMA -> LDS demand ~41 us/CU < matrix
// floor ~66 us/CU. acc[4][4] f32x4 = 64 AGPR. (512,3) caps regalloc (R1
// spill lesson) while permitting 2 blocks/CU.
// Sweep 0: exact fp32 row minima of g = E_j - 2*M_bf16 (cross-wave combine
// via rowmin_l[64][8]); sweep 1: identical recompute, emit g <= rowmin + W.
// [R4 lesson: tile-skip predicates via DPP+f16 cost more VALU than the
// skipped MFMAs saved - do not reintroduce without cheaper predicate.]
__global__ __launch_bounds__(512, 3) void filter2_kernel(
    const float* __restrict__ z, const short* __restrict__ ebuf,
    const float* __restrict__ E, int* __restrict__ cnt_g,
    int* __restrict__ cand_g) {
  __shared__ __align__(16) short Ab[32 * 512];   // 32 KB, fragment-major
  __shared__ float rowmin_l[64][8];
  __shared__ float thr_l[64];
  __shared__ int   cnt_l[64];
  __shared__ int   cand_l[64][8];

  const int t = threadIdx.x;
  const int w = t >> 6, lane = t & 63;
  const int quad = lane >> 4, l16 = lane & 15;
  const int nb = blockIdx.x * 64;
  const int b = nb >> 10, hwb = nb & 1023;   // 64 | 1024: no b straddle

  // ---- cooperative A stage: wave w converts k-slice ks=w, mt=0..3 ----
  {
    const float* zb2 = z + (size_t)b * (DIM * HW_) + hwb;
    const int k0 = w * 32 + quad * 8;
#pragma unroll
    for (int mt = 0; mt < 4; ++mt) {
      const int r = mt * 16 + l16;
      short tmp[8];
#pragma unroll
      for (int i = 0; i < 8; ++i)
        tmp[i] = (short)f2bf(zb2[(size_t)(k0 + i) * HW_ + r]);
      *(bf16x8*)(Ab + ((mt * 8 + w) * 64 + lane) * 8) = *(bf16x8*)tmp;
    }
  }
  __syncthreads();

  const f32x4 zero = {0.0f, 0.0f, 0.0f, 0.0f};
  const short* Abl = Ab + lane * 8;          // per-thread frag base

  // ================= sweep 0: row minima =================
  float runmin[4][4];
#pragma unroll
  for (int mt = 0; mt < 4; ++mt)
#pragma unroll
    for (int rg = 0; rg < 4; ++rg) runmin[mt][rg] = 3.0e38f;

#pragma unroll 1
  for (int grp = 0; grp < 8; ++grp) {
    const int jb = w * 512 + grp * 64;
    const int g16b = jb >> 4;
    f32x4 acc[4][4];
#pragma unroll
    for (int jt = 0; jt < 4; ++jt)
#pragma unroll
      for (int mt = 0; mt < 4; ++mt) acc[jt][mt] = zero;
#pragma unroll 1
    for (int ks = 0; ks < 8; ++ks) {
      bf16x8 av[4];
#pragma unroll
      for (int mt = 0; mt < 4; ++mt)
        av[mt] = *(const bf16x8*)(Abl + (mt * 8 + ks) * 512);
#pragma unroll
      for (int jt = 0; jt < 4; ++jt) {
        bf16x8 bfr = *(const bf16x8*)(ebuf +
            ((size_t)(g16b + jt) * 8 + ks) * 512 + lane * 8);
#pragma unroll
        for (int mt = 0; mt < 4; ++mt)
          acc[jt][mt] = __builtin_amdgcn_mfma_f32_16x16x32_bf16(
              av[mt], bfr, acc[jt][mt], 0, 0, 0);
      }
    }
#pragma unroll
    for (int jt = 0; jt < 4; ++jt) {
      float Ej = E[jb + jt * 16 + l16];
#pragma unroll
      for (int mt = 0; mt < 4; ++mt)
#pragma unroll
        for (int rg = 0; rg < 4; ++rg) {
          float g = fmaf(-2.0f, acc[jt][mt][rg], Ej);
          runmin[mt][rg] = fminf(runmin[mt][rg], g);
        }
    }
  }
  // reduce over the 16 j-columns
#pragma unroll
  for (int mt = 0; mt < 4; ++mt)
#pragma unroll
    for (int rg = 0; rg < 4; ++rg) {
      float m = runmin[mt][rg];
#pragma unroll
      for (int mask = 1; mask <= 8; mask <<= 1)
        m = fminf(m, __shfl_xor(m, mask, 64));
      runmin[mt][rg] = m;
    }
  if (l16 == 0) {
#pragma unroll
    for (int mt = 0; mt < 4; ++mt)
#pragma unroll
      for (int rg = 0; rg < 4; ++rg)
        rowmin_l[mt * 16 + quad * 4 + rg][w] = runmin[mt][rg];
  }
  __syncthreads();
  if (t < 64) {
    float m0 = fminf(fminf(rowmin_l[t][0], rowmin_l[t][1]),
                     fminf(rowmin_l[t][2], rowmin_l[t][3]));
    float m1 = fminf(fminf(rowmin_l[t][4], rowmin_l[t][5]),
                     fminf(rowmin_l[t][6], rowmin_l[t][7]));
    thr_l[t] = fminf(m0, m1) + RESCUE_W;
    cnt_l[t] = 0;
  }
  __syncthreads();
  float thrv[4][4];
#pragma unroll
  for (int mt = 0; mt < 4; ++mt)
#pragma unroll
    for (int rg = 0; rg < 4; ++rg)
      thrv[mt][rg] = thr_l[mt * 16 + quad * 4 + rg];

  // ================= sweep 1: emission =================
#pragma unroll 1
  for (int grp = 0; grp < 8; ++grp) {
    const int jb = w * 512 + grp * 64;
    const int g16b = jb >> 4;
    f32x4 acc[4][4];
#pragma unroll
    for (int jt = 0; jt < 4; ++jt)
#pragma unroll
      for (int mt = 0; mt < 4; ++mt) acc[jt][mt] = zero;
#pragma unroll 1
    for (int ks = 0; ks < 8; ++ks) {
      bf16x8 av[4];
#pragma unroll
      for (int mt = 0; mt < 4; ++mt)
        av[mt] = *(const bf16x8*)(Abl + (mt * 8 + ks) * 512);
#pragma unroll
      for (int jt = 0; jt < 4; ++jt) {
        bf16x8 bfr = *(const bf16x8*)(ebuf +
            ((size_t)(g16b + jt) * 8 + ks) * 512 + lane * 8);
#pragma unroll
        for (int mt = 0; mt < 4; ++mt)
          acc[jt][mt] = __builtin_amdgcn_mfma_f32_16x16x32_bf16(
              av[mt], bfr, acc[jt][mt], 0, 0, 0);
      }
    }
#pragma unroll
    for (int jt = 0; jt < 4; ++jt) {
      int jcol = jb + jt * 16 + l16;
      float Ej = E[jcol];
#pragma unroll
      for (int mt = 0; mt < 4; ++mt)
#pragma unroll
        for (int rg = 0; rg < 4; ++rg) {
          float g = fmaf(-2.0f, acc[jt][mt][rg], Ej);
          if (g <= thrv[mt][rg]) {
            int rl = mt * 16 + quad * 4 + rg;
            int slot = atomicAdd(&cnt_l[rl], 1);
            if (slot < 8) cand_l[rl][slot] = jcol;
          }
        }
    }
  }
  __syncthreads();
  if (t < 64) {
    int c = cnt_l[t];
    cnt_g[nb + t] = c;
    int cc = c > 8 ? 8 : c;
    for (int p = 0; p < cc; ++p) cand_g[(size_t)(nb + t) * 8 + p] = cand_l[t][p];
  }
}

// ---------- rescue v2: LDS-staged z tile, exact np-order chains ----------
// 512 blocks x 64 rows. Stage z[64 rows][256 k] fp32 into LDS once
// (transposed, stride XPAD=257 floats: 257 % 32 == 1 -> chain reads
// z_l[t*257+k] hit bank (t+k)%32 = free 2-way; staging writes likewise).
// Replaces the old per-candidate global z re-reads (~c x 134 MB -> 134 MB
// once). S recomputed here from the SAME fp32 values in the SAME numpy
// pairwise order (stride-1 vs stride-HW_ changes only addressing) ->
// bit-identical; prep's S pass dropped on the filter path.
#define XPAD 257
__global__ __launch_bounds__(256, 2) void exact_cand_kernel(
    const float* __restrict__ z, const float* __restrict__ emb,
    const float* __restrict__ E,
    const int* __restrict__ cnt_g, const int* __restrict__ cand_g,
    int* __restrict__ idx_out, float* __restrict__ idxf_out) {
  __shared__ float z_l[64 * XPAD];
  const int t = threadIdx.x;
  const int nb = blockIdx.x * 64;
  const int b = nb >> 10, hwb = nb & 1023;   // 64 | 1024: no b straddle
  const float* zb = z + (size_t)b * (DIM * HW_) + hwb;
#pragma unroll
  for (int i = 0; i < 16; ++i) {
    int flat = i * 256 + t;
    int d = flat >> 4, r4 = flat & 15;
    float4 v = *(const float4*)(zb + (size_t)d * HW_ + r4 * 4);
    z_l[(r4 * 4 + 0) * XPAD + d] = v.x;
    z_l[(r4 * 4 + 1) * XPAD + d] = v.y;
    z_l[(r4 * 4 + 2) * XPAD + d] = v.z;
    z_l[(r4 * 4 + 3) * XPAD + d] = v.w;
  }
  __syncthreads();
  if (t >= 64) return;

  const int row = nb + t;
  const float* zrow = z_l + t * XPAD;      // z[k] at zrow[k], bit-identical
  float s;
  {
    float s0 = np_sumsq_128(zrow, 1);
    float s1 = np_sumsq_128(zrow + 128, 1);
    s = s0 + s1;
  }
  int c = cnt_g[row];
  float bd = 3.0e38f; int bj = 0x7fffffff;
  if (c <= 8) {
    for (int p = 0; p < c; ++p) {
      int j = cand_g[(size_t)row * 8 + p];
      const float* e = emb + (size_t)j * DIM;
      float acc = 0.0f;
#pragma unroll 8
      for (int k4 = 0; k4 < 64; ++k4) {          // sequential k ascending
        float4 ev = *(const float4*)(e + k4 * 4);
        acc = fmaf(zrow[k4 * 4 + 0], ev.x, acc);
        acc = fmaf(zrow[k4 * 4 + 1], ev.y, acc);
        acc = fmaf(zrow[k4 * 4 + 2], ev.z, acc);
        acc = fmaf(zrow[k4 * 4 + 3], ev.w, acc);
      }
      float d = fmaf(-2.0f, acc, s + E[j]);
      if (d < bd || (d == bd && j < bj)) { bd = d; bj = j; }
    }
  } else {
    for (int j = 0; j < KEMB; ++j) {             // overflow fallback (P~0)
      const float* e = emb + (size_t)j * DIM;
      float acc = 0.0f;
      for (int k4 = 0; k4 < 64; ++k4) {
        float4 ev = *(const float4*)(e + k4 * 4);
        acc = fmaf(zrow[k4 * 4 + 0], ev.x, acc);
        acc = fmaf(zrow[k4 * 4 + 1], ev.y, acc);
        acc = fmaf(zrow[k4 * 4 + 2], ev.z, acc);
        acc = fmaf(zrow[k4 * 4 + 3], ev.w, acc);
      }
      float d = fmaf(-2.0f, acc, s + E[j]);
      if (d < bd || (d == bd && j < bj)) { bd = d; bj = j; }
    }
  }
  idx_out[row] = bj;
  idxf_out[row] = (float)bj;
}

// ---------- fallback fp32 kernel (R2 version, known-passing) ----------
#define RT 64
#define JT 256
#define KC 16
__global__ __launch_bounds__(256, 2) void dist_argmin_kernel(
    const float* __restrict__ z, const float* __restrict__ emb,
    const float* __restrict__ S, const float* __restrict__ E,
    int* __restrict__ idx_out, float* __restrict__ idxf_out) {
  __shared__ float zt[DIM * RT];
  __shared__ float et[KC * JT];
  const int t  = threadIdx.x;
  const int g  = t & 31;
  const int tr = t >> 5;
  const int nb = blockIdx.x * RT;
  const int b  = nb >> 10;
  const int hwb = nb & 1023;
  const float* zb = z + (size_t)b * (DIM * HW_) + hwb;
#pragma unroll
  for (int i = 0; i < 16; ++i) {
    int flat = t + i * 256;
    int k  = flat >> 4;
    int r4 = flat & 15;
    float4 v = *(const float4*)(zb + (size_t)k * HW_ + r4 * 4);
    *(float4*)(zt + flat * 4) = v;
  }
  float bestd[8];
  int   bestj[8];
#pragma unroll
  for (int i = 0; i < 8; ++i) { bestd[i] = 3.0e38f; bestj[i] = 0; }
  float Sreg[8];
#pragma unroll
  for (int rr = 0; rr < 8; ++rr) Sreg[rr] = S[nb + tr * 8 + rr];
  float4 pf[4];
#pragma unroll
  for (int q = 0; q < 4; ++q) {
    int cid = q * 256 + t;
    pf[q] = *(const float4*)(emb + (size_t)(cid >> 2) * DIM + (cid & 3) * 4);
  }
  for (int jt = 0; jt < KEMB / JT; ++jt) {
    float acc[8][8];
#pragma unroll
    for (int rr = 0; rr < 8; ++rr)
#pragma unroll
      for (int c = 0; c < 8; ++c) acc[rr][c] = 0.0f;
    for (int kc = 0; kc < DIM / KC; ++kc) {
      __syncthreads();
#pragma unroll
      for (int q = 0; q < 4; ++q) {
        int cid = q * 256 + t;
        int j = cid >> 2, k4 = cid & 3;
        et[(k4 * 4 + 0) * JT + j] = pf[q].x;
        et[(k4 * 4 + 1) * JT + j] = pf[q].y;
        et[(k4 * 4 + 2) * JT + j] = pf[q].z;
        et[(k4 * 4 + 3) * JT + j] = pf[q].w;
      }
      int s = jt * (DIM / KC) + kc + 1;
      if (s < (KEMB / JT) * (DIM / KC)) {
        int njt = s >> 4, nkc = s & 15;
        const float* base = emb + (size_t)njt * JT * DIM + nkc * KC;
#pragma unroll
        for (int q = 0; q < 4; ++q) {
          int cid = q * 256 + t;
          pf[q] = *(const float4*)(base + (size_t)(cid >> 2) * DIM + (cid & 3) * 4);
        }
      }
      __syncthreads();
      const float* ztk = zt + (kc * KC) * RT;
#pragma unroll
      for (int kk = 0; kk < KC; ++kk) {
        float4 z0 = *(const float4*)(ztk + kk * RT + tr * 8);
        float4 z1 = *(const float4*)(ztk + kk * RT + tr * 8 + 4);
        float2 e0 = *(const float2*)(et + kk * JT + g * 2);
        float2 e1 = *(const float2*)(et + kk * JT + 64 + g * 2);
        float2 e2 = *(const float2*)(et + kk * JT + 128 + g * 2);
        float2 e3 = *(const float2*)(et + kk * JT + 192 + g * 2);
        float zr[8] = {z0.x, z0.y, z0.z, z0.w, z1.x, z1.y, z1.z, z1.w};
        float ev[8] = {e0.x, e0.y, e1.x, e1.y, e2.x, e2.y, e3.x, e3.y};
#pragma unroll
        for (int rr = 0; rr < 8; ++rr)
#pragma unroll
          for (int c = 0; c < 8; ++c)
            acc[rr][c] = fmaf(zr[rr], ev[c], acc[rr][c]);
      }
    }
    int jb = jt * JT;
    float Ereg[8];
#pragma unroll
    for (int c = 0; c < 8; ++c)
      Ereg[c] = E[jb + (c >> 1) * 64 + g * 2 + (c & 1)];
#pragma unroll
    for (int rr = 0; rr < 8; ++rr)
#pragma unroll
      for (int c = 0; c < 8; ++c) {
        float A = Sreg[rr] + Ereg[c];
        float d = fmaf(-2.0f, acc[rr][c], A);
        int j = jb + (c >> 1) * 64 + g * 2 + (c & 1);
        if (d < bestd[rr] || (d == bestd[rr] && j < bestj[rr])) {
          bestd[rr] = d; bestj[rr] = j;
        }
      }
  }
  __syncthreads();
  float* rd = et;
  int*   rj = (int*)(et + 2048);
#pragma unroll
  for (int rr = 0; rr < 8; ++rr) {
    rd[(tr * 8 + rr) * 32 + g] = bestd[rr];
    rj[(tr * 8 + rr) * 32 + g] = bestj[rr];
  }
  __syncthreads();
  if (t < RT) {
    float bd = rd[t * 32];
    int   bj = rj[t * 32];
    for (int c = 1; c < 32; ++c) {
      float d2 = rd[t * 32 + c];
      int   j2 = rj[t * 32 + c];
      if (d2 < bd || (d2 == bd && j2 < bj)) { bd = d2; bj = j2; }
    }
    idx_out[nb + t]  = bj;
    idxf_out[nb + t] = (float)bj;
  }
}

// ---------- epilogue v2 (R9-proven): LDS-staged gather + STE + loss ----------
#define EPAD 257
__global__ __launch_bounds__(256) void epilogue_kernel(
    const float* __restrict__ z, const float* __restrict__ emb,
    const int* __restrict__ idx, float* __restrict__ out0,
    double* __restrict__ loss_sum, int* __restrict__ done,
    float* __restrict__ out_loss) {
#pragma clang fp contract(off)
  __shared__ float eq[64 * EPAD];
  __shared__ int   iv_l[64];
  __shared__ double wsum[4];
  const int t = threadIdx.x, w = t >> 6, lane = t & 63;
  const int nb = blockIdx.x * 64;
  const int b = nb >> 10, hwb = nb & 1023;

  if (t < 64) iv_l[t] = idx[nb + t];
  __syncthreads();
  const float4* emb4 = (const float4*)emb;
#pragma unroll
  for (int i = 0; i < 16; ++i) {
    int r = w * 16 + i;
    float4 v = emb4[(size_t)iv_l[r] * 64 + lane];
    *(float4*)(eq + r * EPAD + lane * 4) = v;
  }
  __syncthreads();

  double acc = 0.0;
  const float* zb = z + (size_t)b * (DIM * HW_) + hwb;
  float* ob = out0 + (size_t)b * (DIM * HW_) + hwb;
  for (int dc = 0; dc < 64; ++dc) {
    int d = dc * 4 + w;
    float zp = zb[(size_t)d * HW_ + lane];
    float zq = eq[lane * EPAD + d];
    float td = zq - zp;                   // fl(z_q - zp)
    ob[(size_t)d * HW_ + lane] = zp + td; // fl(zp + fl(z_q - zp))
    acc += (double)(td * td);
  }
#pragma unroll
  for (int off = 32; off > 0; off >>= 1) acc += __shfl_down(acc, off, 64);
  if (lane == 0) wsum[w] = acc;
  __syncthreads();
  if (t == 0) {
    double bsum = (wsum[0] + wsum[1]) + (wsum[2] + wsum[3]);
    atomicAdd(loss_sum, bsum);
    __threadfence();
    int prev = atomicAdd(done, 1);
    if (prev == 511) {
      double m = loss_sum[0] / 8388608.0;
      float mf = (float)m;
      float bb = 10.0f * mf;
      out_loss[0] = mf + bb;
    }
  }
}

extern "C" void kernel_launch(void* const* d_in, const int* in_sizes, int n_in,
                              void* d_out, int out_size, void* d_ws, size_t ws_size,
                              hipStream_t stream) {
  const float* z   = (const float*)d_in[0];
  const float* emb = (const float*)d_in[1];
  float* out = (float*)d_out;
  char* ws = (char*)d_ws;
  int*      idx  = (int*)ws;
  float*    S    = (float*)(ws + WS_S_OFF);
  float*    E    = (float*)(ws + WS_E_OFF);
  double*   ls   = (double*)(ws + WS_LOSS_OFF);
  int*      done = (int*)(ws + WS_DONE_OFF);
  int*      cnt  = (int*)(ws + WS_CNT_OFF);
  int*      cand = (int*)(ws + WS_CAND_OFF);
  short*    ebuf = (short*)(ws + WS_EBUF_OFF);

  const int do_filter = (ws_size >= (size_t)WS_NEEDED) ? 1 : 0;

  prep_kernel<<<656, 256, 0, stream>>>(z, emb, S, E, ebuf, ls, done, do_filter);

  if (do_filter) {
    filter2_kernel<<<512, 512, 0, stream>>>(z, ebuf, E, cnt, cand);
    exact_cand_kernel<<<512, 256, 0, stream>>>(z, emb, E, cnt, cand, idx,
                                               out + 8388609);
  } else {
    dist_argmin_kernel<<<NROWS / RT, 256, 0, stream>>>(z, emb, S, E, idx,
                                                       out + 8388609);
  }

  epilogue_kernel<<<512, 256, 0, stream>>>(z, emb, idx, out, ls, done,
                                           out + 8388608);
}